// Round 1
// baseline (119.205 us; speedup 1.0000x reference)
//
#include <hip/hip_runtime.h>

#define NB 16
#define LD 128
#define OD 512
#define NS 16384
#define NMB (NS/64 + NB)   // 272 max 64-row padded tiles

typedef __attribute__((ext_vector_type(8))) short short8;
typedef __attribute__((ext_vector_type(4))) float f32x4;

// ---- ws byte layout ----
#define WS_COUNTS  0              // 16 int
#define WS_CURSORS 64             // 16 int
#define WS_OFF     128            // 17 int
#define WS_POFF    256            // 17 int
#define WS_PERM    1024           // NS int (64 KiB)
#define WS_W1B     (128*1024)                    // 16*512*128 bf16 = 2 MiB
#define WS_W2B     (WS_W1B + 2*1024*1024)        // 16*512*512 bf16 = 8 MiB
#define WS_HID     (WS_W2B + 8*1024*1024)        // (NS+NB*64)*512 bf16 ≈ 17 MiB

static __device__ __forceinline__ unsigned short f2bf(float f) {
  unsigned int u = __float_as_uint(f);
  u += 0x7FFFu + ((u >> 16) & 1u);      // RNE
  return (unsigned short)(u >> 16);
}

__global__ void k_init(int* counts, int* cursors) {
  int t = threadIdx.x;
  if (t < NB) { counts[t] = 0; cursors[t] = 0; }
}

__global__ void k_hist(const int* __restrict__ c, int* __restrict__ counts) {
  __shared__ int h[NB];
  if (threadIdx.x < NB) h[threadIdx.x] = 0;
  __syncthreads();
  for (int i = blockIdx.x * blockDim.x + threadIdx.x; i < NS; i += gridDim.x * blockDim.x)
    atomicAdd(&h[c[i]], 1);
  __syncthreads();
  if (threadIdx.x < NB) atomicAdd(&counts[threadIdx.x], h[threadIdx.x]);
}

__global__ void k_prefix(const int* __restrict__ counts, int* __restrict__ off,
                         int* __restrict__ poff) {
  if (threadIdx.x == 0) {
    int o = 0, p = 0;
    for (int e = 0; e < NB; ++e) {
      off[e] = o; poff[e] = p;
      o += counts[e];
      p += ((counts[e] + 63) >> 6) << 6;
    }
    off[NB] = o; poff[NB] = p;
  }
}

__global__ void k_scatter(const int* __restrict__ c, const int* __restrict__ off,
                          int* __restrict__ cursors, int* __restrict__ perm) {
  for (int i = blockIdx.x * blockDim.x + threadIdx.x; i < NS; i += gridDim.x * blockDim.x) {
    int e = c[i];
    int pos = atomicAdd(&cursors[e], 1);
    perm[off[e] + pos] = i;
  }
}

__global__ void k_conv(const float* __restrict__ W1, const float* __restrict__ W2,
                       unsigned short* __restrict__ W1b, unsigned short* __restrict__ W2b) {
  const int n1 = NB * OD * LD / 4, n2 = NB * OD * OD / 4;
  for (int i = blockIdx.x * blockDim.x + threadIdx.x; i < n1 + n2;
       i += gridDim.x * blockDim.x) {
    float4 v; unsigned short* dst;
    if (i < n1) { v = ((const float4*)W1)[i]; dst = W1b + (size_t)i * 4; }
    else        { v = ((const float4*)W2)[i - n1]; dst = W2b + (size_t)(i - n1) * 4; }
    ushort4 o = make_ushort4(f2bf(v.x), f2bf(v.y), f2bf(v.z), f2bf(v.w));
    *(ushort4*)dst = o;
  }
}

// ---------- GEMM1: hidden = relu(lat @ W1^T + b1), lat built on the fly ----------
__global__ __launch_bounds__(256) void k_gemm1(
    const float* __restrict__ eps, const float* __restrict__ mu,
    const float* __restrict__ sigma, const float* __restrict__ b1,
    const unsigned short* __restrict__ W1b,
    const int* __restrict__ off, const int* __restrict__ poff,
    const int* __restrict__ perm, unsigned short* __restrict__ hidden) {
  __shared__ alignas(16) unsigned short As[64 * 136];
  __shared__ alignas(16) unsigned short Bs[64 * 136];
  __shared__ alignas(16) float s_sig[LD];
  __shared__ alignas(16) float s_mu[LD];

  const int mt = blockIdx.y, ct = blockIdx.x;
  const int pr0 = mt * 64;
  if (pr0 >= poff[NB]) return;                  // uniform early-out
  int e = 0;
  while (e < NB - 1 && poff[e + 1] <= pr0) e++;
  const int off_e = off[e];
  const int cnt   = off[e + 1] - off_e;
  const int l0    = pr0 - poff[e];

  const int t = threadIdx.x;
  if (t < LD) s_sig[t] = sigma[e * LD + t];
  else if (t < 2 * LD) s_mu[t - LD] = mu[e * LD + (t - LD)];
  __syncthreads();

  // ---- stage A (lat 64x128 -> bf16, padded 136) ----
  const int r = t >> 2, cseg = (t & 3) * 32;
  {
    int lrow = l0 + r;
    int k = (lrow < cnt) ? perm[off_e + lrow] : 0;
    const f32x4* eps4 = (const f32x4*)(eps + (size_t)k * LD + cseg);
    for (int j = 0; j < 8; ++j) {
      f32x4 v  = eps4[j];
      f32x4 sg = *(const f32x4*)(s_sig + cseg + j * 4);
      f32x4 m  = *(const f32x4*)(s_mu + cseg + j * 4);
      v = v * sg + m;
      ushort4 o = make_ushort4(f2bf(v[0]), f2bf(v[1]), f2bf(v[2]), f2bf(v[3]));
      *(ushort4*)(As + r * 136 + cseg + j * 4) = o;
    }
    // ---- stage B (W1b tile 64x128) ----
    const unsigned short* w1row =
        W1b + ((size_t)e * OD + ct * 64 + r) * LD + cseg;
    for (int j = 0; j < 4; ++j)
      *(uint4*)(Bs + r * 136 + cseg + j * 8) = *(const uint4*)(w1row + j * 8);
  }
  __syncthreads();

  const int lane = t & 63, w = t >> 6;
  const int wr = w >> 1, wc = w & 1;
  const int fr = lane & 15, fg = lane >> 4;
  f32x4 acc[2][2] = {};
  for (int ks = 0; ks < 4; ++ks) {
    short8 a[2], b[2];
    for (int fm = 0; fm < 2; ++fm)
      a[fm] = *(const short8*)(As + (wr * 32 + fm * 16 + fr) * 136 + ks * 32 + fg * 8);
    for (int fn = 0; fn < 2; ++fn)
      b[fn] = *(const short8*)(Bs + (wc * 32 + fn * 16 + fr) * 136 + ks * 32 + fg * 8);
    for (int fm = 0; fm < 2; ++fm)
      for (int fn = 0; fn < 2; ++fn)
        acc[fm][fn] = __builtin_amdgcn_mfma_f32_16x16x32_bf16(a[fm], b[fn], acc[fm][fn], 0, 0, 0);
  }

  // ---- epilogue: bias + relu -> bf16 hidden at padded rows ----
  const int colb = ct * 64 + wc * 32;
  float bv[2];
  bv[0] = b1[e * OD + colb + fr];
  bv[1] = b1[e * OD + colb + 16 + fr];
  for (int fm = 0; fm < 2; ++fm) {
    const int row0 = pr0 + wr * 32 + fm * 16 + fg * 4;
    for (int j = 0; j < 4; ++j)
      for (int fn = 0; fn < 2; ++fn) {
        float vv = acc[fm][fn][j] + bv[fn];
        vv = fmaxf(vv, 0.f);
        hidden[(size_t)(row0 + j) * OD + colb + fn * 16 + fr] = f2bf(vv);
      }
  }
}

// ---------- GEMM2: out = hidden @ W2^T + b2, scatter rows via perm ----------
__global__ __launch_bounds__(256) void k_gemm2(
    const float* __restrict__ b2, const unsigned short* __restrict__ W2b,
    const unsigned short* __restrict__ hidden,
    const int* __restrict__ off, const int* __restrict__ poff,
    const int* __restrict__ perm, float* __restrict__ out) {
  __shared__ alignas(16) unsigned short As[64 * 136];
  __shared__ alignas(16) unsigned short Bs[64 * 136];

  const int mt = blockIdx.y, ct = blockIdx.x;
  const int pr0 = mt * 64;
  if (pr0 >= poff[NB]) return;
  int e = 0;
  while (e < NB - 1 && poff[e + 1] <= pr0) e++;
  const int off_e = off[e];
  const int cnt   = off[e + 1] - off_e;
  const int l0    = pr0 - poff[e];

  const int t = threadIdx.x, r = t >> 2, cseg = (t & 3) * 32;
  const int lane = t & 63, w = t >> 6;
  const int wr = w >> 1, wc = w & 1;
  const int fr = lane & 15, fg = lane >> 4;

  f32x4 acc[2][2] = {};
  for (int kt = 0; kt < 4; ++kt) {
    const unsigned short* ap = hidden + (size_t)(pr0 + r) * OD + kt * 128 + cseg;
    const unsigned short* bp =
        W2b + ((size_t)e * OD + ct * 64 + r) * OD + kt * 128 + cseg;
    for (int j = 0; j < 4; ++j) {
      uint4 va = *(const uint4*)(ap + j * 8);
      uint4 vb = *(const uint4*)(bp + j * 8);
      *(uint4*)(As + r * 136 + cseg + j * 8) = va;
      *(uint4*)(Bs + r * 136 + cseg + j * 8) = vb;
    }
    __syncthreads();
    for (int ks = 0; ks < 4; ++ks) {
      short8 a[2], b[2];
      for (int fm = 0; fm < 2; ++fm)
        a[fm] = *(const short8*)(As + (wr * 32 + fm * 16 + fr) * 136 + ks * 32 + fg * 8);
      for (int fn = 0; fn < 2; ++fn)
        b[fn] = *(const short8*)(Bs + (wc * 32 + fn * 16 + fr) * 136 + ks * 32 + fg * 8);
      for (int fm = 0; fm < 2; ++fm)
        for (int fn = 0; fn < 2; ++fn)
          acc[fm][fn] = __builtin_amdgcn_mfma_f32_16x16x32_bf16(a[fm], b[fn], acc[fm][fn], 0, 0, 0);
    }
    __syncthreads();
  }

  const int colb = ct * 64 + wc * 32;
  float bv[2];
  bv[0] = b2[e * OD + colb + fr];
  bv[1] = b2[e * OD + colb + 16 + fr];
  for (int fm = 0; fm < 2; ++fm) {
    const int rl0 = wr * 32 + fm * 16 + fg * 4;
    for (int j = 0; j < 4; ++j) {
      const int lr = l0 + rl0 + j;
      if (lr < cnt) {
        const int k = perm[off_e + lr];
        for (int fn = 0; fn < 2; ++fn)
          out[(size_t)k * OD + colb + fn * 16 + fr] = acc[fm][fn][j] + bv[fn];
      }
    }
  }
}

extern "C" void kernel_launch(void* const* d_in, const int* in_sizes, int n_in,
                              void* d_out, int out_size, void* d_ws, size_t ws_size,
                              hipStream_t stream) {
  const float* eps   = (const float*)d_in[1];
  const int*   c     = (const int*)d_in[2];
  const float* mu    = (const float*)d_in[3];
  const float* sigma = (const float*)d_in[4];
  const float* W1    = (const float*)d_in[5];
  const float* b1    = (const float*)d_in[6];
  const float* W2    = (const float*)d_in[7];
  const float* b2    = (const float*)d_in[8];
  float* out = (float*)d_out;
  char*  ws  = (char*)d_ws;

  int* counts  = (int*)(ws + WS_COUNTS);
  int* cursors = (int*)(ws + WS_CURSORS);
  int* off     = (int*)(ws + WS_OFF);
  int* poff    = (int*)(ws + WS_POFF);
  int* perm    = (int*)(ws + WS_PERM);
  unsigned short* W1b = (unsigned short*)(ws + WS_W1B);
  unsigned short* W2b = (unsigned short*)(ws + WS_W2B);
  unsigned short* hid = (unsigned short*)(ws + WS_HID);

  k_init<<<1, 64, 0, stream>>>(counts, cursors);
  k_hist<<<64, 256, 0, stream>>>(c, counts);
  k_prefix<<<1, 64, 0, stream>>>(counts, off, poff);
  k_scatter<<<64, 256, 0, stream>>>(c, off, cursors, perm);
  k_conv<<<2048, 256, 0, stream>>>(W1, W2, W1b, W2b);
  k_gemm1<<<dim3(8, NMB), 256, 0, stream>>>(eps, mu, sigma, b1, W1b, off, poff, perm, hid);
  k_gemm2<<<dim3(8, NMB), 256, 0, stream>>>(b2, W2b, hid, off, poff, perm, out);
}

// Round 2
// 78.929 us; speedup vs baseline: 1.5103x; 1.5103x over previous
//
#include <hip/hip_runtime.h>

#define NB 16
#define LD 128
#define OD 512
#define NS 16384
#define NMB (NS/64 + NB)   // 272 max 64-row padded tiles

typedef __attribute__((ext_vector_type(8))) short short8;
typedef __attribute__((ext_vector_type(4))) float f32x4;

// ---- ws byte layout ----
#define WS_OFF     128            // 17 int
#define WS_POFF    256            // 17 int
#define WS_PERM    1024           // NS int (64 KiB)
#define WS_W1B     (128*1024)                    // 16*512*128 bf16 = 2 MiB
#define WS_W2B     (WS_W1B + 2*1024*1024)        // 16*512*512 bf16 = 8 MiB
#define WS_HID     (WS_W2B + 8*1024*1024)        // (NS+NB*64)*512 bf16 ≈ 17 MiB

static __device__ __forceinline__ unsigned short f2bf(float f) {
  unsigned int u = __float_as_uint(f);
  u += 0x7FFFu + ((u >> 16) & 1u);      // RNE
  return (unsigned short)(u >> 16);
}

// ---- fused deterministic counting sort: counts + scan + scatter, 1 block ----
#define SORT_T 1024
#define SORT_CH (NS / SORT_T)   // 16 elements per thread
__global__ __launch_bounds__(SORT_T) void k_sort(
    const int* __restrict__ c, int* __restrict__ off, int* __restrict__ poff,
    int* __restrict__ perm) {
  __shared__ int cnt[NB * SORT_T];   // 64 KiB; bank(e*1024+t) = t%32 -> conflict-free
  __shared__ int totals[NB];
  __shared__ int ebase[NB];

  const int t = threadIdx.x;
  // zero counts
  for (int e = 0; e < NB; ++e) cnt[e * SORT_T + t] = 0;
  __syncthreads();

  // count (exclusive per-thread slots, no atomics)
  int myc[SORT_CH];
  for (int i = 0; i < SORT_CH; ++i) {
    int e = c[t * SORT_CH + i];
    myc[i] = e;
    cnt[e * SORT_T + t]++;
  }
  __syncthreads();

  // per-expert scan across the 1024 thread-counts: wave w handles expert w
  const int w = t >> 6, l = t & 63;
  {
    int carry = 0;
    for (int chunk = 0; chunk < SORT_T / 64; ++chunk) {
      int idx = chunk * 64 + l;
      int v0 = cnt[w * SORT_T + idx];
      int v = v0;
      for (int d = 1; d < 64; d <<= 1) {
        int n = __shfl_up(v, d);
        if (l >= d) v += n;
      }
      cnt[w * SORT_T + idx] = carry + (v - v0);   // exclusive prefix
      carry += __shfl(v, 63);
    }
    if (l == 0) totals[w] = carry;
  }
  __syncthreads();

  // expert-level scan (serial, 16 steps)
  if (t == 0) {
    int o = 0, p = 0;
    for (int e = 0; e < NB; ++e) {
      off[e] = o; poff[e] = p; ebase[e] = o;
      o += totals[e];
      p += ((totals[e] + 63) >> 6) << 6;
    }
    off[NB] = o; poff[NB] = p;
  }
  __syncthreads();

  // stable scatter, no atomics (each (e,t) cursor exclusively owned)
  for (int i = 0; i < SORT_CH; ++i) {
    int e = myc[i];
    int pos = ebase[e] + cnt[e * SORT_T + t]++;
    perm[pos] = t * SORT_CH + i;
  }
}

__global__ void k_conv(const float* __restrict__ W1, const float* __restrict__ W2,
                       unsigned short* __restrict__ W1b, unsigned short* __restrict__ W2b) {
  const int n1 = NB * OD * LD / 4, n2 = NB * OD * OD / 4;
  for (int i = blockIdx.x * blockDim.x + threadIdx.x; i < n1 + n2;
       i += gridDim.x * blockDim.x) {
    float4 v; unsigned short* dst;
    if (i < n1) { v = ((const float4*)W1)[i]; dst = W1b + (size_t)i * 4; }
    else        { v = ((const float4*)W2)[i - n1]; dst = W2b + (size_t)(i - n1) * 4; }
    ushort4 o = make_ushort4(f2bf(v.x), f2bf(v.y), f2bf(v.z), f2bf(v.w));
    *(ushort4*)dst = o;
  }
}

// ---------- GEMM1: hidden = relu(lat @ W1^T + b1), lat built on the fly ----------
__global__ __launch_bounds__(256) void k_gemm1(
    const float* __restrict__ eps, const float* __restrict__ mu,
    const float* __restrict__ sigma, const float* __restrict__ b1,
    const unsigned short* __restrict__ W1b,
    const int* __restrict__ off, const int* __restrict__ poff,
    const int* __restrict__ perm, unsigned short* __restrict__ hidden) {
  __shared__ alignas(16) unsigned short As[64 * 136];
  __shared__ alignas(16) unsigned short Bs[64 * 136];
  __shared__ alignas(16) float s_sig[LD];
  __shared__ alignas(16) float s_mu[LD];

  const int mt = blockIdx.y, ct = blockIdx.x;
  const int pr0 = mt * 64;
  if (pr0 >= poff[NB]) return;                  // uniform early-out
  int e = 0;
  while (e < NB - 1 && poff[e + 1] <= pr0) e++;
  const int off_e = off[e];
  const int cnt   = off[e + 1] - off_e;
  const int l0    = pr0 - poff[e];

  const int t = threadIdx.x;
  if (t < LD) s_sig[t] = sigma[e * LD + t];
  else if (t < 2 * LD) s_mu[t - LD] = mu[e * LD + (t - LD)];
  __syncthreads();

  // ---- stage A (lat 64x128 -> bf16, padded 136) ----
  const int r = t >> 2, cseg = (t & 3) * 32;
  {
    int lrow = l0 + r;
    int k = (lrow < cnt) ? perm[off_e + lrow] : 0;
    const f32x4* eps4 = (const f32x4*)(eps + (size_t)k * LD + cseg);
    for (int j = 0; j < 8; ++j) {
      f32x4 v  = eps4[j];
      f32x4 sg = *(const f32x4*)(s_sig + cseg + j * 4);
      f32x4 m  = *(const f32x4*)(s_mu + cseg + j * 4);
      v = v * sg + m;
      ushort4 o = make_ushort4(f2bf(v[0]), f2bf(v[1]), f2bf(v[2]), f2bf(v[3]));
      *(ushort4*)(As + r * 136 + cseg + j * 4) = o;
    }
    // ---- stage B (W1b tile 64x128) ----
    const unsigned short* w1row =
        W1b + ((size_t)e * OD + ct * 64 + r) * LD + cseg;
    for (int j = 0; j < 4; ++j)
      *(uint4*)(Bs + r * 136 + cseg + j * 8) = *(const uint4*)(w1row + j * 8);
  }
  __syncthreads();

  const int lane = t & 63, w = t >> 6;
  const int wr = w >> 1, wc = w & 1;
  const int fr = lane & 15, fg = lane >> 4;
  f32x4 acc[2][2] = {};
  for (int ks = 0; ks < 4; ++ks) {
    short8 a[2], b[2];
    for (int fm = 0; fm < 2; ++fm)
      a[fm] = *(const short8*)(As + (wr * 32 + fm * 16 + fr) * 136 + ks * 32 + fg * 8);
    for (int fn = 0; fn < 2; ++fn)
      b[fn] = *(const short8*)(Bs + (wc * 32 + fn * 16 + fr) * 136 + ks * 32 + fg * 8);
    for (int fm = 0; fm < 2; ++fm)
      for (int fn = 0; fn < 2; ++fn)
        acc[fm][fn] = __builtin_amdgcn_mfma_f32_16x16x32_bf16(a[fm], b[fn], acc[fm][fn], 0, 0, 0);
  }

  // ---- epilogue: bias + relu -> bf16 hidden at padded rows ----
  const int colb = ct * 64 + wc * 32;
  float bv[2];
  bv[0] = b1[e * OD + colb + fr];
  bv[1] = b1[e * OD + colb + 16 + fr];
  for (int fm = 0; fm < 2; ++fm) {
    const int row0 = pr0 + wr * 32 + fm * 16 + fg * 4;
    for (int j = 0; j < 4; ++j)
      for (int fn = 0; fn < 2; ++fn) {
        float vv = acc[fm][fn][j] + bv[fn];
        vv = fmaxf(vv, 0.f);
        hidden[(size_t)(row0 + j) * OD + colb + fn * 16 + fr] = f2bf(vv);
      }
  }
}

// ---------- GEMM2: out = hidden @ W2^T + b2, scatter rows via perm ----------
__global__ __launch_bounds__(256) void k_gemm2(
    const float* __restrict__ b2, const unsigned short* __restrict__ W2b,
    const unsigned short* __restrict__ hidden,
    const int* __restrict__ off, const int* __restrict__ poff,
    const int* __restrict__ perm, float* __restrict__ out) {
  __shared__ alignas(16) unsigned short As[64 * 136];
  __shared__ alignas(16) unsigned short Bs[64 * 136];

  const int mt = blockIdx.y, ct = blockIdx.x;
  const int pr0 = mt * 64;
  if (pr0 >= poff[NB]) return;
  int e = 0;
  while (e < NB - 1 && poff[e + 1] <= pr0) e++;
  const int off_e = off[e];
  const int cnt   = off[e + 1] - off_e;
  const int l0    = pr0 - poff[e];

  const int t = threadIdx.x, r = t >> 2, cseg = (t & 3) * 32;
  const int lane = t & 63, w = t >> 6;
  const int wr = w >> 1, wc = w & 1;
  const int fr = lane & 15, fg = lane >> 4;

  f32x4 acc[2][2] = {};
  for (int kt = 0; kt < 4; ++kt) {
    const unsigned short* ap = hidden + (size_t)(pr0 + r) * OD + kt * 128 + cseg;
    const unsigned short* bp =
        W2b + ((size_t)e * OD + ct * 64 + r) * OD + kt * 128 + cseg;
    for (int j = 0; j < 4; ++j) {
      uint4 va = *(const uint4*)(ap + j * 8);
      uint4 vb = *(const uint4*)(bp + j * 8);
      *(uint4*)(As + r * 136 + cseg + j * 8) = va;
      *(uint4*)(Bs + r * 136 + cseg + j * 8) = vb;
    }
    __syncthreads();
    for (int ks = 0; ks < 4; ++ks) {
      short8 a[2], b[2];
      for (int fm = 0; fm < 2; ++fm)
        a[fm] = *(const short8*)(As + (wr * 32 + fm * 16 + fr) * 136 + ks * 32 + fg * 8);
      for (int fn = 0; fn < 2; ++fn)
        b[fn] = *(const short8*)(Bs + (wc * 32 + fn * 16 + fr) * 136 + ks * 32 + fg * 8);
      for (int fm = 0; fm < 2; ++fm)
        for (int fn = 0; fn < 2; ++fn)
          acc[fm][fn] = __builtin_amdgcn_mfma_f32_16x16x32_bf16(a[fm], b[fn], acc[fm][fn], 0, 0, 0);
    }
    __syncthreads();
  }

  const int colb = ct * 64 + wc * 32;
  float bv[2];
  bv[0] = b2[e * OD + colb + fr];
  bv[1] = b2[e * OD + colb + 16 + fr];
  for (int fm = 0; fm < 2; ++fm) {
    const int rl0 = wr * 32 + fm * 16 + fg * 4;
    for (int j = 0; j < 4; ++j) {
      const int lr = l0 + rl0 + j;
      if (lr < cnt) {
        const int k = perm[off_e + lr];
        for (int fn = 0; fn < 2; ++fn)
          out[(size_t)k * OD + colb + fn * 16 + fr] = acc[fm][fn][j] + bv[fn];
      }
    }
  }
}

extern "C" void kernel_launch(void* const* d_in, const int* in_sizes, int n_in,
                              void* d_out, int out_size, void* d_ws, size_t ws_size,
                              hipStream_t stream) {
  const float* eps   = (const float*)d_in[1];
  const int*   c     = (const int*)d_in[2];
  const float* mu    = (const float*)d_in[3];
  const float* sigma = (const float*)d_in[4];
  const float* W1    = (const float*)d_in[5];
  const float* b1    = (const float*)d_in[6];
  const float* W2    = (const float*)d_in[7];
  const float* b2    = (const float*)d_in[8];
  float* out = (float*)d_out;
  char*  ws  = (char*)d_ws;

  int* off     = (int*)(ws + WS_OFF);
  int* poff    = (int*)(ws + WS_POFF);
  int* perm    = (int*)(ws + WS_PERM);
  unsigned short* W1b = (unsigned short*)(ws + WS_W1B);
  unsigned short* W2b = (unsigned short*)(ws + WS_W2B);
  unsigned short* hid = (unsigned short*)(ws + WS_HID);

  k_sort<<<1, SORT_T, 0, stream>>>(c, off, poff, perm);
  k_conv<<<2048, 256, 0, stream>>>(W1, W2, W1b, W2b);
  k_gemm1<<<dim3(8, NMB), 256, 0, stream>>>(eps, mu, sigma, b1, W1b, off, poff, perm, hid);
  k_gemm2<<<dim3(8, NMB), 256, 0, stream>>>(b2, W2b, hid, off, poff, perm, out);
}

// Round 3
// 71.689 us; speedup vs baseline: 1.6628x; 1.1010x over previous
//
#include <hip/hip_runtime.h>

#define NB 16
#define LD 128
#define OD 512
#define NS 16384
#define NPMAX (NS + NB*128)      // 18432 max padded rows (128-aligned segments)
#define NMT (NPMAX/128)          // 144 max M-tiles

typedef __attribute__((ext_vector_type(8))) short short8;
typedef __attribute__((ext_vector_type(4))) float f32x4;

// ---- ws byte layout ----
#define WS_OFF     128                           // 17 int
#define WS_POFF    256                           // 17 int
#define WS_PERM    1024                          // NS int (64 KiB)
#define WS_W1B     (128*1024)                    // 16*512*128 bf16 = 2 MiB
#define WS_W2B     (WS_W1B + 2*1024*1024)        // 16*512*512 bf16 = 8 MiB
#define WS_HID     (WS_W2B + 8*1024*1024)        // NPMAX*512 bf16 = 18.9 MiB
#define WS_LAT     (WS_HID + 20*1024*1024)       // NPMAX*128 bf16 = 4.7 MiB

#define GLDS16(g, l) __builtin_amdgcn_global_load_lds( \
    (const __attribute__((address_space(1))) unsigned int*)(g), \
    (__attribute__((address_space(3))) unsigned int*)(l), 16, 0, 0)

static __device__ __forceinline__ unsigned short f2bf(float f) {
  unsigned int u = __float_as_uint(f);
  u += 0x7FFFu + ((u >> 16) & 1u);      // RNE
  return (unsigned short)(u >> 16);
}

// ---- fused deterministic counting sort: counts + scan + scatter, 1 block ----
#define SORT_T 1024
#define SORT_CH (NS / SORT_T)
__global__ __launch_bounds__(SORT_T) void k_sort(
    const int* __restrict__ c, int* __restrict__ off, int* __restrict__ poff,
    int* __restrict__ perm) {
  __shared__ int cnt[NB * SORT_T];
  __shared__ int totals[NB];
  __shared__ int ebase[NB];

  const int t = threadIdx.x;
  for (int e = 0; e < NB; ++e) cnt[e * SORT_T + t] = 0;
  __syncthreads();

  int myc[SORT_CH];
  for (int i = 0; i < SORT_CH; ++i) {
    int e = c[t * SORT_CH + i];
    myc[i] = e;
    cnt[e * SORT_T + t]++;
  }
  __syncthreads();

  const int w = t >> 6, l = t & 63;
  {
    int carry = 0;
    for (int chunk = 0; chunk < SORT_T / 64; ++chunk) {
      int idx = chunk * 64 + l;
      int v0 = cnt[w * SORT_T + idx];
      int v = v0;
      for (int d = 1; d < 64; d <<= 1) {
        int n = __shfl_up(v, d);
        if (l >= d) v += n;
      }
      cnt[w * SORT_T + idx] = carry + (v - v0);
      carry += __shfl(v, 63);
    }
    if (l == 0) totals[w] = carry;
  }
  __syncthreads();

  if (t == 0) {
    int o = 0, p = 0;
    for (int e = 0; e < NB; ++e) {
      off[e] = o; poff[e] = p; ebase[e] = o;
      o += totals[e];
      p += ((totals[e] + 127) >> 7) << 7;    // pad segments to 128 rows
    }
    off[NB] = o; poff[NB] = p;
  }
  __syncthreads();

  for (int i = 0; i < SORT_CH; ++i) {
    int e = myc[i];
    int pos = ebase[e] + cnt[e * SORT_T + t]++;
    perm[pos] = t * SORT_CH + i;
  }
}

__global__ void k_conv(const float* __restrict__ W1, const float* __restrict__ W2,
                       unsigned short* __restrict__ W1b, unsigned short* __restrict__ W2b) {
  const int n1 = NB * OD * LD / 4, n2 = NB * OD * OD / 4;
  for (int i = blockIdx.x * blockDim.x + threadIdx.x; i < n1 + n2;
       i += gridDim.x * blockDim.x) {
    float4 v; unsigned short* dst;
    if (i < n1) { v = ((const float4*)W1)[i]; dst = W1b + (size_t)i * 4; }
    else        { v = ((const float4*)W2)[i - n1]; dst = W2b + (size_t)(i - n1) * 4; }
    ushort4 o = make_ushort4(f2bf(v.x), f2bf(v.y), f2bf(v.z), f2bf(v.w));
    *(ushort4*)dst = o;
  }
}

// ---- build permuted bf16 latent: lat[p] = eps[perm[p]]*sigma[e]+mu[e], 0 for pad ----
__global__ __launch_bounds__(256) void k_lat(
    const float* __restrict__ eps, const float* __restrict__ mu,
    const float* __restrict__ sigma,
    const int* __restrict__ off, const int* __restrict__ poff,
    const int* __restrict__ perm, unsigned short* __restrict__ lat) {
  const int p0 = blockIdx.x * 8;                 // 8 rows/block, never straddles segment
  if (p0 >= poff[NB]) return;
  int e = 0;
  while (e < NB - 1 && poff[e + 1] <= p0) e++;
  const int off_e = off[e], cnt = off[e + 1] - off_e;
  const int t = threadIdx.x;
  const int p = p0 + (t >> 5), col = (t & 31) * 4;
  const int lrow = p - poff[e];
  ushort4 o;
  if (lrow < cnt) {
    int src = perm[off_e + lrow];
    float4 v  = *(const float4*)(eps + (size_t)src * LD + col);
    float4 sg = *(const float4*)(sigma + e * LD + col);
    float4 m  = *(const float4*)(mu + e * LD + col);
    o = make_ushort4(f2bf(v.x * sg.x + m.x), f2bf(v.y * sg.y + m.y),
                     f2bf(v.z * sg.z + m.z), f2bf(v.w * sg.w + m.w));
  } else {
    o = make_ushort4(0, 0, 0, 0);
  }
  *(ushort4*)(lat + (size_t)p * LD + col) = o;
}

// ---------- GEMM1: hidden = relu(lat @ W1^T + b1) — m97 structure, K=128 ----------
__global__ __launch_bounds__(256) void k_gemm1(
    const float* __restrict__ b1, const unsigned short* __restrict__ W1b,
    const unsigned short* __restrict__ lat,
    const int* __restrict__ poff, unsigned short* __restrict__ hidden) {
  __shared__ alignas(16) unsigned short As[128 * 64];
  __shared__ alignas(16) unsigned short Bs[128 * 64];

  const int mt = blockIdx.y, ct = blockIdx.x;
  const int pr0 = mt * 128;
  if (pr0 >= poff[NB]) return;
  int e = 0;
  while (e < NB - 1 && poff[e + 1] <= pr0) e++;

  const int t = threadIdx.x, w = t >> 6, lane = t & 63;
  const int wr = w >> 1, wc = w & 1;
  const int fr = lane & 15, fg = lane >> 4;
  const int srow = lane >> 3, scol = (lane & 7) * 8;

  f32x4 acc[4][4] = {};
  for (int kt = 0; kt < 2; ++kt) {
#pragma unroll
    for (int i = 0; i < 4; ++i) {
      const int ci = w * 4 + i;
      const int row = ci * 8 + srow;
      GLDS16(lat + (size_t)(pr0 + row) * LD + kt * 64 + scol, As + ci * 512);
      GLDS16(W1b + ((size_t)e * OD + ct * 128 + row) * LD + kt * 64 + scol, Bs + ci * 512);
    }
    __syncthreads();
#pragma unroll
    for (int ks = 0; ks < 2; ++ks) {
      short8 a[4], b[4];
#pragma unroll
      for (int fm = 0; fm < 4; ++fm)
        a[fm] = *(const short8*)(As + (wr * 64 + fm * 16 + fr) * 64 + ks * 32 + fg * 8);
#pragma unroll
      for (int fn = 0; fn < 4; ++fn)
        b[fn] = *(const short8*)(Bs + (wc * 64 + fn * 16 + fr) * 64 + ks * 32 + fg * 8);
#pragma unroll
      for (int fm = 0; fm < 4; ++fm)
#pragma unroll
        for (int fn = 0; fn < 4; ++fn)
          acc[fm][fn] = __builtin_amdgcn_mfma_f32_16x16x32_bf16(a[fm], b[fn], acc[fm][fn], 0, 0, 0);
    }
    __syncthreads();
  }

  const int colb = ct * 128 + wc * 64;
  float bias[4];
#pragma unroll
  for (int fn = 0; fn < 4; ++fn) bias[fn] = b1[e * OD + colb + fn * 16 + fr];
#pragma unroll
  for (int fm = 0; fm < 4; ++fm) {
    const int row0 = pr0 + wr * 64 + fm * 16 + fg * 4;
#pragma unroll
    for (int j = 0; j < 4; ++j) {
      unsigned short* hrow = hidden + (size_t)(row0 + j) * OD + colb;
#pragma unroll
      for (int fn = 0; fn < 4; ++fn)
        hrow[fn * 16 + fr] = f2bf(fmaxf(acc[fm][fn][j] + bias[fn], 0.f));
    }
  }
}

// ---------- GEMM2: out = hidden @ W2^T + b2, scatter rows — m97 structure, K=512 ----------
__global__ __launch_bounds__(256) void k_gemm2(
    const float* __restrict__ b2, const unsigned short* __restrict__ W2b,
    const unsigned short* __restrict__ hidden,
    const int* __restrict__ off, const int* __restrict__ poff,
    const int* __restrict__ perm, float* __restrict__ out) {
  __shared__ alignas(16) unsigned short As[128 * 64];
  __shared__ alignas(16) unsigned short Bs[128 * 64];

  const int mt = blockIdx.y, ct = blockIdx.x;
  const int pr0 = mt * 128;
  if (pr0 >= poff[NB]) return;
  int e = 0;
  while (e < NB - 1 && poff[e + 1] <= pr0) e++;
  const int off_e = off[e];
  const int cnt   = off[e + 1] - off_e;
  const int l0    = pr0 - poff[e];

  const int t = threadIdx.x, w = t >> 6, lane = t & 63;
  const int wr = w >> 1, wc = w & 1;
  const int fr = lane & 15, fg = lane >> 4;
  const int srow = lane >> 3, scol = (lane & 7) * 8;

  f32x4 acc[4][4] = {};
  for (int kt = 0; kt < 8; ++kt) {
#pragma unroll
    for (int i = 0; i < 4; ++i) {
      const int ci = w * 4 + i;
      const int row = ci * 8 + srow;
      GLDS16(hidden + (size_t)(pr0 + row) * OD + kt * 64 + scol, As + ci * 512);
      GLDS16(W2b + ((size_t)e * OD + ct * 128 + row) * OD + kt * 64 + scol, Bs + ci * 512);
    }
    __syncthreads();
#pragma unroll
    for (int ks = 0; ks < 2; ++ks) {
      short8 a[4], b[4];
#pragma unroll
      for (int fm = 0; fm < 4; ++fm)
        a[fm] = *(const short8*)(As + (wr * 64 + fm * 16 + fr) * 64 + ks * 32 + fg * 8);
#pragma unroll
      for (int fn = 0; fn < 4; ++fn)
        b[fn] = *(const short8*)(Bs + (wc * 64 + fn * 16 + fr) * 64 + ks * 32 + fg * 8);
#pragma unroll
      for (int fm = 0; fm < 4; ++fm)
#pragma unroll
        for (int fn = 0; fn < 4; ++fn)
          acc[fm][fn] = __builtin_amdgcn_mfma_f32_16x16x32_bf16(a[fm], b[fn], acc[fm][fn], 0, 0, 0);
    }
    __syncthreads();
  }

  const int colb = ct * 128 + wc * 64;
  float bias[4];
#pragma unroll
  for (int fn = 0; fn < 4; ++fn) bias[fn] = b2[e * OD + colb + fn * 16 + fr];
#pragma unroll
  for (int fm = 0; fm < 4; ++fm) {
    const int rl0 = wr * 64 + fm * 16 + fg * 4;
#pragma unroll
    for (int j = 0; j < 4; ++j) {
      const int lr = l0 + rl0 + j;
      if (lr < cnt) {
        const int k = perm[off_e + lr];
        float* orow = out + (size_t)k * OD + colb;
#pragma unroll
        for (int fn = 0; fn < 4; ++fn)
          orow[fn * 16 + fr] = acc[fm][fn][j] + bias[fn];
      }
    }
  }
}

extern "C" void kernel_launch(void* const* d_in, const int* in_sizes, int n_in,
                              void* d_out, int out_size, void* d_ws, size_t ws_size,
                              hipStream_t stream) {
  const float* eps   = (const float*)d_in[1];
  const int*   c     = (const int*)d_in[2];
  const float* mu    = (const float*)d_in[3];
  const float* sigma = (const float*)d_in[4];
  const float* W1    = (const float*)d_in[5];
  const float* b1    = (const float*)d_in[6];
  const float* W2    = (const float*)d_in[7];
  const float* b2    = (const float*)d_in[8];
  float* out = (float*)d_out;
  char*  ws  = (char*)d_ws;

  int* off     = (int*)(ws + WS_OFF);
  int* poff    = (int*)(ws + WS_POFF);
  int* perm    = (int*)(ws + WS_PERM);
  unsigned short* W1b = (unsigned short*)(ws + WS_W1B);
  unsigned short* W2b = (unsigned short*)(ws + WS_W2B);
  unsigned short* hid = (unsigned short*)(ws + WS_HID);
  unsigned short* lat = (unsigned short*)(ws + WS_LAT);

  k_conv<<<2048, 256, 0, stream>>>(W1, W2, W1b, W2b);
  k_sort<<<1, SORT_T, 0, stream>>>(c, off, poff, perm);
  k_lat<<<NPMAX / 8, 256, 0, stream>>>(eps, mu, sigma, off, poff, perm, lat);
  k_gemm1<<<dim3(4, NMT), 256, 0, stream>>>(b1, W1b, lat, poff, hid);
  k_gemm2<<<dim3(4, NMT), 256, 0, stream>>>(b2, W2b, hid, off, poff, perm, out);
}

// Round 4
// 66.560 us; speedup vs baseline: 1.7910x; 1.0771x over previous
//
#include <hip/hip_runtime.h>

#define NB 16
#define LD 128
#define OD 512
#define NS 16384
#define NPMAX (NS + NB*128)      // 18432 max padded rows (128-aligned segments)
#define NMT (NPMAX/128)          // 144 max M-tiles

typedef __attribute__((ext_vector_type(8))) short short8;
typedef __attribute__((ext_vector_type(4))) float f32x4;

// ---- ws byte layout ----
#define WS_OFF     128                           // 17 int
#define WS_POFF    256                           // 17 int
#define WS_PERM    1024                          // NS int (64 KiB)
#define WS_W1B     (128*1024)                    // 16*512*128 bf16 = 2 MiB
#define WS_W2B     (WS_W1B + 2*1024*1024)        // 16*512*512 bf16 = 8 MiB
#define WS_HID     (WS_W2B + 8*1024*1024)        // NPMAX*512 bf16 = 18.9 MiB
#define WS_LAT     (WS_HID + 20*1024*1024)       // NPMAX*128 bf16 = 4.7 MiB

#define GLDS16(g, l) __builtin_amdgcn_global_load_lds( \
    (const __attribute__((address_space(1))) unsigned int*)(g), \
    (__attribute__((address_space(3))) unsigned int*)(l), 16, 0, 0)

static __device__ __forceinline__ unsigned short f2bf(float f) {
  unsigned int u = __float_as_uint(f);
  u += 0x7FFFu + ((u >> 16) & 1u);      // RNE
  return (unsigned short)(u >> 16);
}

// ---- fused: block 0 = counting sort (1024 thr); blocks 1.. = weight conv ----
#define SORT_T 1024
#define SORT_CH (NS / SORT_T)
__global__ __launch_bounds__(SORT_T) void k_convsort(
    const float* __restrict__ W1, const float* __restrict__ W2,
    const int* __restrict__ c,
    unsigned short* __restrict__ W1b, unsigned short* __restrict__ W2b,
    int* __restrict__ off, int* __restrict__ poff, int* __restrict__ perm) {
  __shared__ int cnt[NB * SORT_T];   // 64 KiB (sort block only; costs conv occupancy, fine)
  __shared__ int totals[NB];
  __shared__ int ebase[NB];

  const int t = threadIdx.x;
  if (blockIdx.x == 0) {
    for (int e = 0; e < NB; ++e) cnt[e * SORT_T + t] = 0;
    __syncthreads();

    int myc[SORT_CH];
    for (int i = 0; i < SORT_CH; ++i) {
      int e = c[t * SORT_CH + i];
      myc[i] = e;
      cnt[e * SORT_T + t]++;
    }
    __syncthreads();

    const int w = t >> 6, l = t & 63;
    {
      int carry = 0;
      for (int chunk = 0; chunk < SORT_T / 64; ++chunk) {
        int idx = chunk * 64 + l;
        int v0 = cnt[w * SORT_T + idx];
        int v = v0;
        for (int d = 1; d < 64; d <<= 1) {
          int n = __shfl_up(v, d);
          if (l >= d) v += n;
        }
        cnt[w * SORT_T + idx] = carry + (v - v0);
        carry += __shfl(v, 63);
      }
      if (l == 0) totals[w] = carry;
    }
    __syncthreads();

    if (t == 0) {
      int o = 0, p = 0;
      for (int e = 0; e < NB; ++e) {
        off[e] = o; poff[e] = p; ebase[e] = o;
        o += totals[e];
        p += ((totals[e] + 127) >> 7) << 7;    // pad segments to 128 rows
      }
      off[NB] = o; poff[NB] = p;
    }
    __syncthreads();

    for (int i = 0; i < SORT_CH; ++i) {
      int e = myc[i];
      int pos = ebase[e] + cnt[e * SORT_T + t]++;
      perm[pos] = t * SORT_CH + i;
    }
  } else {
    const int n1 = NB * OD * LD / 4, n2 = NB * OD * OD / 4;
    for (int i = (blockIdx.x - 1) * SORT_T + t; i < n1 + n2;
         i += (gridDim.x - 1) * SORT_T) {
      float4 v; unsigned short* dst;
      if (i < n1) { v = ((const float4*)W1)[i]; dst = W1b + (size_t)i * 4; }
      else        { v = ((const float4*)W2)[i - n1]; dst = W2b + (size_t)(i - n1) * 4; }
      ushort4 o = make_ushort4(f2bf(v.x), f2bf(v.y), f2bf(v.z), f2bf(v.w));
      *(ushort4*)dst = o;
    }
  }
}

// ---- build permuted bf16 latent; XCD-swizzled to match gemm1's mt map ----
__global__ __launch_bounds__(256) void k_lat(
    const float* __restrict__ eps, const float* __restrict__ mu,
    const float* __restrict__ sigma,
    const int* __restrict__ off, const int* __restrict__ poff,
    const int* __restrict__ perm, unsigned short* __restrict__ lat) {
  const int L = blockIdx.x;                      // 2304 = 8 * 288
  const int b = (L & 7) * 288 + (L >> 3);        // bijective XCD-chunk swizzle
  const int p0 = b * 8;                          // 8 rows/block
  if (p0 >= poff[NB]) return;
  int e = 0;
  while (e < NB - 1 && poff[e + 1] <= p0) e++;
  const int off_e = off[e], cnt = off[e + 1] - off_e;
  const int t = threadIdx.x;
  const int p = p0 + (t >> 5), col = (t & 31) * 4;
  const int lrow = p - poff[e];
  ushort4 o;
  if (lrow < cnt) {
    int src = perm[off_e + lrow];
    float4 v  = *(const float4*)(eps + (size_t)src * LD + col);
    float4 sg = *(const float4*)(sigma + e * LD + col);
    float4 m  = *(const float4*)(mu + e * LD + col);
    o = make_ushort4(f2bf(v.x * sg.x + m.x), f2bf(v.y * sg.y + m.y),
                     f2bf(v.z * sg.z + m.z), f2bf(v.w * sg.w + m.w));
  } else {
    o = make_ushort4(0, 0, 0, 0);
  }
  *(ushort4*)(lat + (size_t)p * LD + col) = o;
}

// ---------- GEMM1: hidden = relu(lat @ W1^T + b1) — m97 structure, K=128 ----------
__global__ __launch_bounds__(256) void k_gemm1(
    const float* __restrict__ b1, const unsigned short* __restrict__ W1b,
    const unsigned short* __restrict__ lat,
    const int* __restrict__ poff, unsigned short* __restrict__ hidden) {
  __shared__ alignas(16) unsigned short As[128 * 64];
  __shared__ alignas(16) unsigned short Bs[128 * 64];

  const int L = blockIdx.x;                      // 576 = 8 * 72
  const int s = (L & 7) * 72 + (L >> 3);         // XCD-chunk: 18 mts per XCD, all 4 cts
  const int mt = s >> 2, ct = s & 3;
  const int pr0 = mt * 128;
  if (pr0 >= poff[NB]) return;
  int e = 0;
  while (e < NB - 1 && poff[e + 1] <= pr0) e++;

  const int t = threadIdx.x, w = t >> 6, lane = t & 63;
  const int wr = w >> 1, wc = w & 1;
  const int fr = lane & 15, fg = lane >> 4;
  const int srow = lane >> 3, scol = (lane & 7) * 8;

  f32x4 acc[4][4] = {};
  for (int kt = 0; kt < 2; ++kt) {
#pragma unroll
    for (int i = 0; i < 4; ++i) {
      const int ci = w * 4 + i;
      const int row = ci * 8 + srow;
      GLDS16(lat + (size_t)(pr0 + row) * LD + kt * 64 + scol, As + ci * 512);
      GLDS16(W1b + ((size_t)e * OD + ct * 128 + row) * LD + kt * 64 + scol, Bs + ci * 512);
    }
    __syncthreads();
#pragma unroll
    for (int ks = 0; ks < 2; ++ks) {
      short8 a[4], b[4];
#pragma unroll
      for (int fm = 0; fm < 4; ++fm)
        a[fm] = *(const short8*)(As + (wr * 64 + fm * 16 + fr) * 64 + ks * 32 + fg * 8);
#pragma unroll
      for (int fn = 0; fn < 4; ++fn)
        b[fn] = *(const short8*)(Bs + (wc * 64 + fn * 16 + fr) * 64 + ks * 32 + fg * 8);
#pragma unroll
      for (int fm = 0; fm < 4; ++fm)
#pragma unroll
        for (int fn = 0; fn < 4; ++fn)
          acc[fm][fn] = __builtin_amdgcn_mfma_f32_16x16x32_bf16(a[fm], b[fn], acc[fm][fn], 0, 0, 0);
    }
    __syncthreads();
  }

  const int colb = ct * 128 + wc * 64;
  float bias[4];
#pragma unroll
  for (int fn = 0; fn < 4; ++fn) bias[fn] = b1[e * OD + colb + fn * 16 + fr];
#pragma unroll
  for (int fm = 0; fm < 4; ++fm) {
    const int row0 = pr0 + wr * 64 + fm * 16 + fg * 4;
#pragma unroll
    for (int j = 0; j < 4; ++j) {
      unsigned short* hrow = hidden + (size_t)(row0 + j) * OD + colb;
#pragma unroll
      for (int fn = 0; fn < 4; ++fn)
        hrow[fn * 16 + fr] = f2bf(fmaxf(acc[fm][fn][j] + bias[fn], 0.f));
    }
  }
}

// ---------- GEMM2: out = hidden @ W2^T + b2, scatter rows — m97 structure, K=512 ----------
__global__ __launch_bounds__(256) void k_gemm2(
    const float* __restrict__ b2, const unsigned short* __restrict__ W2b,
    const unsigned short* __restrict__ hidden,
    const int* __restrict__ off, const int* __restrict__ poff,
    const int* __restrict__ perm, float* __restrict__ out) {
  __shared__ alignas(16) unsigned short As[128 * 64];
  __shared__ alignas(16) unsigned short Bs[128 * 64];

  const int L = blockIdx.x;                      // 576 = 8 * 72, same map as gemm1
  const int s = (L & 7) * 72 + (L >> 3);
  const int mt = s >> 2, ct = s & 3;
  const int pr0 = mt * 128;
  if (pr0 >= poff[NB]) return;
  int e = 0;
  while (e < NB - 1 && poff[e + 1] <= pr0) e++;
  const int off_e = off[e];
  const int cnt   = off[e + 1] - off_e;
  const int l0    = pr0 - poff[e];

  const int t = threadIdx.x, w = t >> 6, lane = t & 63;
  const int wr = w >> 1, wc = w & 1;
  const int fr = lane & 15, fg = lane >> 4;
  const int srow = lane >> 3, scol = (lane & 7) * 8;

  f32x4 acc[4][4] = {};
  for (int kt = 0; kt < 8; ++kt) {
#pragma unroll
    for (int i = 0; i < 4; ++i) {
      const int ci = w * 4 + i;
      const int row = ci * 8 + srow;
      GLDS16(hidden + (size_t)(pr0 + row) * OD + kt * 64 + scol, As + ci * 512);
      GLDS16(W2b + ((size_t)e * OD + ct * 128 + row) * OD + kt * 64 + scol, Bs + ci * 512);
    }
    __syncthreads();
#pragma unroll
    for (int ks = 0; ks < 2; ++ks) {
      short8 a[4], b[4];
#pragma unroll
      for (int fm = 0; fm < 4; ++fm)
        a[fm] = *(const short8*)(As + (wr * 64 + fm * 16 + fr) * 64 + ks * 32 + fg * 8);
#pragma unroll
      for (int fn = 0; fn < 4; ++fn)
        b[fn] = *(const short8*)(Bs + (wc * 64 + fn * 16 + fr) * 64 + ks * 32 + fg * 8);
#pragma unroll
      for (int fm = 0; fm < 4; ++fm)
#pragma unroll
        for (int fn = 0; fn < 4; ++fn)
          acc[fm][fn] = __builtin_amdgcn_mfma_f32_16x16x32_bf16(a[fm], b[fn], acc[fm][fn], 0, 0, 0);
    }
    __syncthreads();
  }

  const int colb = ct * 128 + wc * 64;
  float bias[4];
#pragma unroll
  for (int fn = 0; fn < 4; ++fn) bias[fn] = b2[e * OD + colb + fn * 16 + fr];
#pragma unroll
  for (int fm = 0; fm < 4; ++fm) {
    const int rl0 = wr * 64 + fm * 16 + fg * 4;
#pragma unroll
    for (int j = 0; j < 4; ++j) {
      const int lr = l0 + rl0 + j;
      if (lr < cnt) {
        const int k = perm[off_e + lr];
        float* orow = out + (size_t)k * OD + colb;
#pragma unroll
        for (int fn = 0; fn < 4; ++fn)
          orow[fn * 16 + fr] = acc[fm][fn][j] + bias[fn];
      }
    }
  }
}

extern "C" void kernel_launch(void* const* d_in, const int* in_sizes, int n_in,
                              void* d_out, int out_size, void* d_ws, size_t ws_size,
                              hipStream_t stream) {
  const float* eps   = (const float*)d_in[1];
  const int*   c     = (const int*)d_in[2];
  const float* mu    = (const float*)d_in[3];
  const float* sigma = (const float*)d_in[4];
  const float* W1    = (const float*)d_in[5];
  const float* b1    = (const float*)d_in[6];
  const float* W2    = (const float*)d_in[7];
  const float* b2    = (const float*)d_in[8];
  float* out = (float*)d_out;
  char*  ws  = (char*)d_ws;

  int* off     = (int*)(ws + WS_OFF);
  int* poff    = (int*)(ws + WS_POFF);
  int* perm    = (int*)(ws + WS_PERM);
  unsigned short* W1b = (unsigned short*)(ws + WS_W1B);
  unsigned short* W2b = (unsigned short*)(ws + WS_W2B);
  unsigned short* hid = (unsigned short*)(ws + WS_HID);
  unsigned short* lat = (unsigned short*)(ws + WS_LAT);

  k_convsort<<<512, SORT_T, 0, stream>>>(W1, W2, c, W1b, W2b, off, poff, perm);
  k_lat<<<2304, 256, 0, stream>>>(eps, mu, sigma, off, poff, perm, lat);
  k_gemm1<<<576, 256, 0, stream>>>(b1, W1b, lat, poff, hid);
  k_gemm2<<<576, 256, 0, stream>>>(b2, W2b, hid, off, poff, perm, out);
}